// Round 7
// baseline (527.838 us; speedup 1.0000x reference)
//
#include <hip/hip_runtime.h>
#include <hip/hip_fp16.h>
#include <stdint.h>

// ---------------------------------------------------------------------------
// QuantizedExpert: out = relu(x @ dq(W1)^T + b1) @ dq(W2)^T + b2
// HARNESS DTYPES: int8 inputs arrive widened to int32; fp16 scales as fp32.
// INT8 MFMA path: weights int4 are exact in int8; x quantized per-token
// (signed, absmax/127); h quantized per-token shifted-u8 (h>=0 after relu:
// store round(h*255/max)-128, corrected by +128*rowsum(W2) in epilogue).
// GEMM v7: r1-r6 showed a single barrier-locked block is bounded by the
// SERIAL SUM of matrix+LDS pipes (~45% MfmaUtil for i8 32x32's 1:1 ratio).
// Fix = cross-block overlap (m114): resize for 2 blocks/CU:
//   tile 128x256, BK=64, 8 waves of 64x64 (acc 64 AGPR; combined regs <=128
//   via __launch_bounds__(512,4) -> 16 waves/CU), LDS 3x24KB triple-buffer
//   (72KB -> 2 blocks resident), counted vmcnt(3) 2-tile prefetch, counted
//   lgkm(4), 1 barrier/tile, 64B-row swizzle key (row>>1)&3 (min-conflict).
// Both GEMM grids now >=2 blocks/CU (gemm2 was 1/CU before - its hidden cost).
// ---------------------------------------------------------------------------

typedef __attribute__((ext_vector_type(4)))  int i32x4;
typedef __attribute__((ext_vector_type(16))) int i32x16;
typedef __attribute__((ext_vector_type(8))) _Float16 f16x8;

__device__ __forceinline__ void load_lds16(const void* g, void* l) {
    __builtin_amdgcn_global_load_lds(
        (__attribute__((address_space(1))) void*)(void*)g,
        (__attribute__((address_space(3))) void*)(void*)l,
        16, 0, 0);
}

__device__ __forceinline__ float block_max(float m, int tid) {
    __shared__ float red[4];
#pragma unroll
    for (int off = 32; off; off >>= 1)
        m = fmaxf(m, __shfl_down(m, off, 64));
    if ((tid & 63) == 0) red[tid >> 6] = m;
    __syncthreads();
    m = fmaxf(fmaxf(red[0], red[1]), fmaxf(red[2], red[3]));
    __syncthreads();
    return m;
}

// ---- x [rows][4096] f32 -> int8 per-row symmetric; sx[row] = absmax/127
__global__ __launch_bounds__(256) void quant_x(
    const float* __restrict__ in, int* __restrict__ out,
    float* __restrict__ rscale, int ncols)
{
    const int tid = threadIdx.x;
    const int row = blockIdx.x;
    const float4* rp = (const float4*)(in + (size_t)row * ncols);
    const int nf4 = ncols / 4;                  // 1024
    float4 v[4];
    float m = 0.f;
#pragma unroll
    for (int k = 0; k < 4; ++k) {
        v[k] = rp[k * 256 + tid];
        m = fmaxf(m, fmaxf(fmaxf(fabsf(v[k].x), fabsf(v[k].y)),
                           fmaxf(fabsf(v[k].z), fabsf(v[k].w))));
    }
    m = block_max(m, tid);
    m = fmaxf(m, 1e-20f);
    const float inv = 127.f / m;
    if (tid == 0) rscale[row] = m / 127.f;
    int* orow = out + (size_t)row * nf4;
#pragma unroll
    for (int k = 0; k < 4; ++k) {
        int q0 = __float2int_rn(v[k].x * inv);
        int q1 = __float2int_rn(v[k].y * inv);
        int q2 = __float2int_rn(v[k].z * inv);
        int q3 = __float2int_rn(v[k].w * inv);
        orow[k * 256 + tid] = (q0 & 0xFF) | ((q1 & 0xFF) << 8) |
                              ((q2 & 0xFF) << 16) | ((q3 & 0xFF) << 24);
    }
}

// ---- h [rows][8192] f16 (>=0) -> shifted u8: round(h*255/max)-128; sh=max/255
__global__ __launch_bounds__(256) void quant_h(
    const _Float16* __restrict__ in, int2* __restrict__ out,
    float* __restrict__ rscale, int ncols)
{
    const int tid = threadIdx.x;
    const int row = blockIdx.x;
    const f16x8* rp = (const f16x8*)(in + (size_t)row * ncols);
    const int nv = ncols / 8;                   // 1024
    f16x8 v[4];
    float m = 0.f;
#pragma unroll
    for (int k = 0; k < 4; ++k) {
        v[k] = rp[k * 256 + tid];
#pragma unroll
        for (int e = 0; e < 8; ++e) m = fmaxf(m, (float)v[k][e]);
    }
    m = block_max(m, tid);
    m = fmaxf(m, 1e-20f);
    const float inv = 255.f / m;
    if (tid == 0) rscale[row] = m / 255.f;
    int2* orow = out + (size_t)row * nv;
#pragma unroll
    for (int k = 0; k < 4; ++k) {
        union { int8_t b[8]; int2 w; } u;
#pragma unroll
        for (int e = 0; e < 8; ++e) {
            int q = __float2int_rn((float)v[k][e] * inv);
            q = q < 0 ? 0 : (q > 255 ? 255 : q);
            u.b[e] = (int8_t)(q - 128);
        }
        orow[k * 256 + tid] = u.w;
    }
}

// ---- packed int4 (one byte per int32 word) -> int8; also row sums (for shift)
__global__ __launch_bounds__(256) void expand_int4_i8(
    const int4* __restrict__ packed, int2* __restrict__ out,
    int* __restrict__ wsum, int n_i4)
{
    const int tid = threadIdx.x;
    const int row = blockIdx.x;
    const int4* prow = packed + (size_t)row * n_i4;
    int2* orow = out + (size_t)row * n_i4;
    int sum = 0;
    for (int j = tid; j < n_i4; j += 256) {
        int4 p = prow[j];
        int vals[4] = {p.x, p.y, p.z, p.w};
        union { int8_t b[8]; int2 w; } u;
#pragma unroll
        for (int b = 0; b < 4; ++b) {
            int by = (int)(int8_t)(vals[b] & 0xFF);
            int hi = by >> 4;
            int lo = ((by & 15) ^ 8) - 8;
            u.b[2 * b] = (int8_t)hi;
            u.b[2 * b + 1] = (int8_t)lo;
            sum += hi + lo;
        }
        orow[j] = u.w;
    }
    __shared__ int sred[4];
#pragma unroll
    for (int off = 32; off; off >>= 1) sum += __shfl_down(sum, off, 64);
    if ((tid & 63) == 0) sred[tid >> 6] = sum;
    __syncthreads();
    if (tid == 0) wsum[row] = sred[0] + sred[1] + sred[2] + sred[3];
}

// ---------------------------------------------------------------------------
// C = epi( A[M][K]i8 @ B[N][K]i8^T );  epi = sa[m]*s[n]*(acc + shift) + bias[n]
// Tile 128(M)x256(N), BK=64B, 8 waves (2M x 4N), wave 64x64 via 2x2
// mfma_i32_32x32x32_i8 (acc 64 AGPR).  LDS: 3 bufs x (A[128][64] 8KB +
// B[256][64] 16KB) = 72KB.  Swizzle: 64B row = 4 chunks of 16B; phys chunk
// q holds logical c = q ^ ((row>>1)&3)  (uniform 4 words/bank on reads =
// b128 minimum; key invariant under row+32 so frag sub-tiles share bases).
//
// Per tile u (buf P = u%3, unrolled x3):
//   vmcnt(3) if u+1<NT else vmcnt(0)   // stage(u) done (issued at u-2);
//                                      // stage(u+1) stays in flight
//   s_barrier                          // buf(u) ready; all waves done with
//                                      // buf(u-1) reads
//   stage(u+2) -> buf((u+2)%3)         // 3 DMA; target buf's readers were
//                                      // tile u-1, fenced by this barrier
//   ds_read ks0(4), ks1(4); lgkm(4) -> MFMA4(ks0); lgkm(0) -> MFMA4(ks1)
// In-order vmcnt/lgkm retirement makes the counted waits exact; tail guards
// degrade counts safely (vmcnt(3) waits oldest-first).
// ---------------------------------------------------------------------------
template <bool RELU, bool SHIFT, typename OutT>
__global__ __launch_bounds__(512, 4) void gemm_i8_v7(
    const int8_t* __restrict__ A, const int8_t* __restrict__ B,
    OutT* __restrict__ C,
    const float* __restrict__ sa,      // per-m dequant scale
    const float* __restrict__ s,       // per-n scale
    const float* __restrict__ bias,    // per-n bias
    const int* __restrict__ wsum,      // per-n row-sum of B (SHIFT only)
    int M, int N, int K)
{
    __shared__ alignas(1024) char sAB[3][24576];

    const int tid  = threadIdx.x;
    const int lane = tid & 63;
    const int wave = tid >> 6;
    const int wm = wave >> 2;          // 0..1: 64-row half
    const int wn = wave & 3;           // 0..3: 64-col quarter

    // Column-major per-XCD mapping (B-panel <=4MB fits XCD-private L2)
    int bid = blockIdx.y * gridDim.x + blockIdx.x;
    const int xcd = bid & 7;
    const int idx = bid >> 3;
    const int cpx = gridDim.x >> 3;
    const int bx = xcd * cpx + idx / gridDim.y;
    const int by = idx % gridDim.y;
    const int bm = by * 128;
    const int bn = bx * 256;

    // ---- staging: thread -> one 16B chunk per region-half.
    // A region 8KB: row = tid>>2 (0..127), phys chunk q = tid&3, logical
    // chunk c = q ^ ((row>>1)&3).  B 16KB: two 128-row sets (key invariant
    // under row+128).
    const int srow = tid >> 2;
    const int sq   = tid & 3;
    const int sc   = sq ^ ((srow >> 1) & 3);
    const int8_t* gA = A + (size_t)(bm + srow) * K + sc * 16;
    const int8_t* gB = B + (size_t)(bn + srow) * K + sc * 16;
    const size_t rK128 = (size_t)128 * K;
    const int ldst = tid * 16;

    // ---- fragment read bases (mfma i8 32x32x32: m/n = lane&31, k-half kh)
    const int l31 = lane & 31;
    const int kh  = lane >> 5;
    const int ra  = wm * 64 + l31;             // A row (i adds 32 -> +2048B)
    const int rb  = wn * 64 + l31;             // B row (j adds 32 -> +2048B)
    const int aks0 = ra * 64 + (((0 + kh) ^ ((ra >> 1) & 3)) << 4);
    const int aks1 = ra * 64 + (((2 + kh) ^ ((ra >> 1) & 3)) << 4);
    const int bks0 = 8192 + rb * 64 + (((0 + kh) ^ ((rb >> 1) & 3)) << 4);
    const int bks1 = 8192 + rb * 64 + (((2 + kh) ^ ((rb >> 1) & 3)) << 4);

    i32x4 afX[2], afY[2], bfX[2], bfY[2];
    i32x16 acc[2][2] = {};
    const int NT = K >> 6;                     // 64 (gemm1) / 128 (gemm2)

#define SB0() __builtin_amdgcn_sched_barrier(0)
#define STAGE(P, kt)                                                        \
    do { const size_t ko = (size_t)(kt) * 64;                               \
        load_lds16(gA + ko, &sAB[P][ldst]);                                 \
        load_lds16(gB + ko, &sAB[P][8192 + ldst]);                          \
        load_lds16(gB + ko + rK128, &sAB[P][16384 + ldst]); } while (0)
#define READF(P)                                                            \
    do { const char* p_ = sAB[P];                                           \
        afX[0] = *(const i32x4*)(p_ + aks0);                                \
        afX[1] = *(const i32x4*)(p_ + aks0 + 2048);                         \
        bfX[0] = *(const i32x4*)(p_ + bks0);                                \
        bfX[1] = *(const i32x4*)(p_ + bks0 + 2048);                         \
        afY[0] = *(const i32x4*)(p_ + aks1);                                \
        afY[1] = *(const i32x4*)(p_ + aks1 + 2048);                         \
        bfY[0] = *(const i32x4*)(p_ + bks1);                                \
        bfY[1] = *(const i32x4*)(p_ + bks1 + 2048); } while (0)
#define MFMA4(AF, BF)                                                       \
    do { _Pragma("unroll")                                                  \
        for (int i_ = 0; i_ < 2; ++i_) {                                    \
            acc[i_][0] = __builtin_amdgcn_mfma_i32_32x32x32_i8(             \
                AF[i_], BF[0], acc[i_][0], 0, 0, 0);                        \
            acc[i_][1] = __builtin_amdgcn_mfma_i32_32x32x32_i8(             \
                AF[i_], BF[1], acc[i_][1], 0, 0, 0);                        \
        } } while (0)
#define TILE(u, P)                                                          \
    if ((u) < NT) {                                                         \
        if ((u) + 1 < NT) asm volatile("s_waitcnt vmcnt(3)" ::: "memory");  \
        else              asm volatile("s_waitcnt vmcnt(0)" ::: "memory");  \
        SB0();                                                              \
        __builtin_amdgcn_s_barrier();                                       \
        SB0();                                                              \
        if ((u) + 2 < NT) STAGE((P + 2) % 3, (u) + 2);                      \
        SB0();                                                              \
        READF(P);                                                           \
        SB0();                                                              \
        asm volatile("s_waitcnt lgkmcnt(4)" ::: "memory");                  \
        SB0();                                                              \
        MFMA4(afX, bfX);                                                    \
        SB0();                                                              \
        asm volatile("s_waitcnt lgkmcnt(0)" ::: "memory");                  \
        SB0();                                                              \
        MFMA4(afY, bfY);                                                    \
    }

    // prologue: buf0 <- tile0, buf1 <- tile1
    STAGE(0, 0);
    if (NT > 1) STAGE(1, 1);

    for (int t = 0; t < NT; t += 3) {
        TILE(t,     0);
        TILE(t + 1, 1);
        TILE(t + 2, 2);
    }
#undef SB0
#undef STAGE
#undef READF
#undef MFMA4
#undef TILE

    // epilogue: 32x32 C/D layout col=lane&31, row=(reg&3)+8*(reg>>2)+4*(lane>>5)
#pragma unroll
    for (int j = 0; j < 2; ++j) {
        const int n  = bn + wn * 64 + j * 32 + l31;
        const float sc2 = s[n];
        const float bs = bias[n];
        const int shf = SHIFT ? 128 * wsum[n] : 0;
#pragma unroll
        for (int i = 0; i < 2; ++i) {
            const int mb = bm + wm * 64 + i * 32 + 4 * kh;
#pragma unroll
            for (int reg = 0; reg < 16; ++reg) {
                const int m = mb + (reg & 3) + 8 * (reg >> 2);
                float v = (float)(acc[i][j][reg] + shf) * sc2 * sa[m] + bs;
                if (RELU) v = v > 0.f ? v : 0.f;
                C[(size_t)m * N + n] = (OutT)v;
            }
        }
    }
}

extern "C" void kernel_launch(void* const* d_in, const int* in_sizes, int n_in,
                              void* d_out, int out_size, void* d_ws, size_t ws_size,
                              hipStream_t stream)
{
    const float* x   = (const float*)d_in[0];
    const int4*  w1p = (const int4*)d_in[1];     // int8 widened to int32
    const float* s1  = (const float*)d_in[2];    // fp16 widened to fp32
    const float* b1  = (const float*)d_in[3];
    const int4*  w2p = (const int4*)d_in[4];
    const float* s2  = (const float*)d_in[5];
    const float* b2  = (const float*)d_in[6];
    float* out = (float*)d_out;

    const int d    = in_sizes[6];        // 4096
    const int d2   = in_sizes[3];        // 8192
    const int Ntok = in_sizes[0] / d;    // 4096

    char* ws = (char*)d_ws;
    int8_t*   xq = (int8_t*)ws;                               // 16.8 MB
    int8_t*   wq = (int8_t*)(ws + (size_t)Ntok * d);          // 33.6 MB (W1/W2 shared)
    _Float16* hb = (_Float16*)(ws + (size_t)Ntok * d + (size_t)d2 * d);        // 67 MB
    int8_t*   hq = (int8_t*)((char*)hb + (size_t)Ntok * d2 * 2);               // 33.6 MB
    float*    sx = (float*)((char*)hq + (size_t)Ntok * d2);   // 16 KB
    float*    sh = sx + Ntok;                                 // 16 KB
    int*      wsum = (int*)(sh + Ntok);                       // 32 KB

    // 1. x -> int8 per-row
    quant_x<<<Ntok, 256, 0, stream>>>(x, (int*)xq, sx, d);
    // 2. W1 int4 -> int8
    expand_int4_i8<<<d2, 256, 0, stream>>>(w1p, (int2*)wq, wsum, d / 8);
    // 3. h = relu(s1[n]*sx[m]*acc + b1[n]) -> f16   grid 32x32 = 1024 blocks
    {
        dim3 grid(d2 / 256, Ntok / 128);
        gemm_i8_v7<true, false, _Float16><<<grid, 512, 0, stream>>>(
            xq, wq, hb, sx, s1, b1, nullptr, Ntok, d2, d);
    }
    // 4. h -> shifted-u8 per-row
    quant_h<<<Ntok, 256, 0, stream>>>(hb, (int2*)hq, sh, d2);
    // 5. W2 int4 -> int8 + row sums
    expand_int4_i8<<<d, 256, 0, stream>>>(w2p, (int2*)wq, wsum, d2 / 8);
    // 6. out = s2[n]*sh[m]*(acc+128*wsum[n]) + b2[n]  grid 16x32 = 512 blocks
    {
        dim3 grid(d / 256, Ntok / 128);
        gemm_i8_v7<false, true, float><<<grid, 512, 0, stream>>>(
            hq, wq, out, sh, s2, b2, wsum, Ntok, d, d2);
    }
}

// Round 8
// 484.296 us; speedup vs baseline: 1.0899x; 1.0899x over previous
//
#include <hip/hip_runtime.h>
#include <hip/hip_fp16.h>
#include <stdint.h>

// ---------------------------------------------------------------------------
// QuantizedExpert: out = relu(x @ dq(W1)^T + b1) @ dq(W2)^T + b2
// HARNESS DTYPES: int8 inputs arrive widened to int32; fp16 scales as fp32.
// INT8 MFMA path: weights int4 are exact in int8; x quantized per-token
// (signed, absmax/127); h quantized per-token shifted-u8 (h>=0 after relu:
// store round(h*255/max)-128, corrected by +128*rowsum(W2) in epilogue).
// GEMM = v6 (best verified): 256x256 tile, BK=128B, 8 waves 2x4,
// mfma_i32_32x32x32_i8, counted lgkm(6)/vmcnt(4), XOR-swizzled LDS,
// zero-VALU addressing (x2 unroll, lane-resident bases), column-XCD map.
// AUX overhaul (r7 accounting: aux+gaps ~200us at 1.9TB/s, 3x off roofline):
//   - ONE fused prep kernel (quant_x + expand W1 + expand W2): 6->4 launches
//   - all aux stores vectorized to 16B int4
//   - ws_size fallback to sequential layout if workspace is tight
// ---------------------------------------------------------------------------

typedef __attribute__((ext_vector_type(4)))  int i32x4;
typedef __attribute__((ext_vector_type(16))) int i32x16;
typedef __attribute__((ext_vector_type(8))) _Float16 f16x8;

__device__ __forceinline__ void load_lds16(const void* g, void* l) {
    __builtin_amdgcn_global_load_lds(
        (__attribute__((address_space(1))) void*)(void*)g,
        (__attribute__((address_space(3))) void*)(void*)l,
        16, 0, 0);
}

__device__ __forceinline__ float block_max_f(float m, int tid) {
    __shared__ float red[4];
#pragma unroll
    for (int off = 32; off; off >>= 1)
        m = fmaxf(m, __shfl_down(m, off, 64));
    if ((tid & 63) == 0) red[tid >> 6] = m;
    __syncthreads();
    m = fmaxf(fmaxf(red[0], red[1]), fmaxf(red[2], red[3]));
    __syncthreads();
    return m;
}

// ---- expand 32B packed-int4-in-int32 -> 16B int8 (nibble order: hi,lo)
__device__ __forceinline__ void expand32(const int4 p0, const int4 p1,
                                         int4* outw, int* sum) {
    union { int8_t b[16]; int4 w; } u;
    int vals[8] = {p0.x, p0.y, p0.z, p0.w, p1.x, p1.y, p1.z, p1.w};
    int s = 0;
#pragma unroll
    for (int b = 0; b < 8; ++b) {
        int by = (int)(int8_t)(vals[b] & 0xFF);
        int hi = by >> 4;
        int lo = ((by & 15) ^ 8) - 8;
        u.b[2 * b]     = (int8_t)hi;
        u.b[2 * b + 1] = (int8_t)lo;
        s += hi + lo;
    }
    *outw = u.w;
    *sum += s;
}

// ---------------------------------------------------------------------------
// Fused prep: blocks [0,Ntok) quant_x row; [Ntok,Ntok+d2) expand W1 row;
// [Ntok+d2, Ntok+d2+d) expand W2 row (+wsum).  256 thr.
// quant_x: thread owns cols 16t..16t+15 -> one int4 store.
// expand:  thread iter owns 32B in -> 16B out, coalesced.
// ---------------------------------------------------------------------------
__global__ __launch_bounds__(256) void prep_fused(
    const float* __restrict__ x, int4* __restrict__ xq, float* __restrict__ sx,
    const int4* __restrict__ w1p, int4* __restrict__ wq1,
    const int4* __restrict__ w2p, int4* __restrict__ wq2,
    int* __restrict__ wsum, int Ntok, int d, int d2)
{
    const int tid = threadIdx.x;
    const int b = blockIdx.x;

    if (b < Ntok) {
        // ---- quant_x row b: read 16 f32, write 16 int8 contiguous
        const float4* r4 = (const float4*)(x + (size_t)b * d);
        float4 v[4];
        float m = 0.f;
#pragma unroll
        for (int k = 0; k < 4; ++k) {
            v[k] = r4[4 * tid + k];
            m = fmaxf(m, fmaxf(fmaxf(fabsf(v[k].x), fabsf(v[k].y)),
                               fmaxf(fabsf(v[k].z), fabsf(v[k].w))));
        }
        m = block_max_f(m, tid);
        m = fmaxf(m, 1e-20f);
        const float inv = 127.f / m;
        if (tid == 0) sx[b] = m / 127.f;
        union { int8_t c[16]; int4 w; } u;
#pragma unroll
        for (int k = 0; k < 4; ++k) {
            u.c[4 * k + 0] = (int8_t)__float2int_rn(v[k].x * inv);
            u.c[4 * k + 1] = (int8_t)__float2int_rn(v[k].y * inv);
            u.c[4 * k + 2] = (int8_t)__float2int_rn(v[k].z * inv);
            u.c[4 * k + 3] = (int8_t)__float2int_rn(v[k].w * inv);
        }
        xq[(size_t)b * (d >> 4) + tid] = u.w;
        return;
    }

    if (b < Ntok + d2) {
        // ---- expand W1 row (n_i4 = d/8 = 512 in-units -> 256 out int4)
        const int row = b - Ntok;
        const int n_i4 = d >> 3;
        const int4* prow = w1p + (size_t)row * n_i4;
        int4* orow = wq1 + (size_t)row * (n_i4 >> 1);
        int dummy = 0;
        for (int j = tid; j < (n_i4 >> 1); j += 256) {
            int4 ow;
            expand32(prow[2 * j], prow[2 * j + 1], &ow, &dummy);
            orow[j] = ow;
        }
        return;
    }

    // ---- expand W2 row (n_i4 = d2/8 = 1024 -> 512 out int4) + wsum
    {
        const int row = b - Ntok - d2;
        const int n_i4 = d2 >> 3;
        const int4* prow = w2p + (size_t)row * n_i4;
        int4* orow = wq2 + (size_t)row * (n_i4 >> 1);
        int sum = 0;
        for (int j = tid; j < (n_i4 >> 1); j += 256) {
            int4 ow;
            expand32(prow[2 * j], prow[2 * j + 1], &ow, &sum);
            orow[j] = ow;
        }
        __shared__ int sred[4];
#pragma unroll
        for (int off = 32; off; off >>= 1) sum += __shfl_down(sum, off, 64);
        if ((tid & 63) == 0) sred[tid >> 6] = sum;
        __syncthreads();
        if (tid == 0) wsum[row] = sred[0] + sred[1] + sred[2] + sred[3];
    }
}

// ---- standalone expand (fallback path when ws is tight; vectorized)
__global__ __launch_bounds__(256) void expand_int4_i8(
    const int4* __restrict__ packed, int4* __restrict__ out,
    int* __restrict__ wsum, int n_i4)
{
    const int tid = threadIdx.x;
    const int row = blockIdx.x;
    const int4* prow = packed + (size_t)row * n_i4;
    int4* orow = out + (size_t)row * (n_i4 >> 1);
    int sum = 0;
    for (int j = tid; j < (n_i4 >> 1); j += 256) {
        int4 ow;
        expand32(prow[2 * j], prow[2 * j + 1], &ow, &sum);
        orow[j] = ow;
    }
    __shared__ int sred[4];
#pragma unroll
    for (int off = 32; off; off >>= 1) sum += __shfl_down(sum, off, 64);
    if ((tid & 63) == 0) sred[tid >> 6] = sum;
    __syncthreads();
    if (tid == 0) wsum[row] = sred[0] + sred[1] + sred[2] + sred[3];
}

// ---- standalone quant_x (fallback; same math, int4 store)
__global__ __launch_bounds__(256) void quant_x(
    const float* __restrict__ in, int4* __restrict__ out,
    float* __restrict__ rscale, int ncols)
{
    const int tid = threadIdx.x;
    const int row = blockIdx.x;
    const float4* r4 = (const float4*)(in + (size_t)row * ncols);
    float4 v[4];
    float m = 0.f;
#pragma unroll
    for (int k = 0; k < 4; ++k) {
        v[k] = r4[4 * tid + k];
        m = fmaxf(m, fmaxf(fmaxf(fabsf(v[k].x), fabsf(v[k].y)),
                           fmaxf(fabsf(v[k].z), fabsf(v[k].w))));
    }
    m = block_max_f(m, tid);
    m = fmaxf(m, 1e-20f);
    const float inv = 127.f / m;
    if (tid == 0) rscale[row] = m / 127.f;
    union { int8_t c[16]; int4 w; } u;
#pragma unroll
    for (int k = 0; k < 4; ++k) {
        u.c[4 * k + 0] = (int8_t)__float2int_rn(v[k].x * inv);
        u.c[4 * k + 1] = (int8_t)__float2int_rn(v[k].y * inv);
        u.c[4 * k + 2] = (int8_t)__float2int_rn(v[k].z * inv);
        u.c[4 * k + 3] = (int8_t)__float2int_rn(v[k].w * inv);
    }
    out[(size_t)row * (ncols >> 4) + tid] = u.w;
}

// ---- h [rows][8192] f16 (>=0) -> shifted u8 (int4 stores); sh=max/255
__global__ __launch_bounds__(256) void quant_h(
    const _Float16* __restrict__ in, int4* __restrict__ out,
    float* __restrict__ rscale, int ncols)
{
    const int tid = threadIdx.x;
    const int row = blockIdx.x;
    const f16x8* rp = (const f16x8*)(in + (size_t)row * ncols);
    f16x8 v[2][2];
    float m = 0.f;
#pragma unroll
    for (int c = 0; c < 2; ++c) {
        const int kc = tid + c * 256;
        v[c][0] = rp[2 * kc];
        v[c][1] = rp[2 * kc + 1];
#pragma unroll
        for (int e = 0; e < 8; ++e)
            m = fmaxf(m, fmaxf((float)v[c][0][e], (float)v[c][1][e]));
    }
    m = block_max_f(m, tid);
    m = fmaxf(m, 1e-20f);
    const float inv = 255.f / m;
    if (tid == 0) rscale[row] = m / 255.f;
#pragma unroll
    for (int c = 0; c < 2; ++c) {
        const int kc = tid + c * 256;
        union { int8_t b[16]; int4 w; } u;
#pragma unroll
        for (int h = 0; h < 2; ++h)
#pragma unroll
            for (int e = 0; e < 8; ++e) {
                int q = __float2int_rn((float)v[c][h][e] * inv);
                q = q < 0 ? 0 : (q > 255 ? 255 : q);
                u.b[8 * h + e] = (int8_t)(q - 128);
            }
        out[(size_t)row * (ncols >> 4) + kc] = u.w;
    }
}

// ---------------------------------------------------------------------------
// GEMM v6 (verbatim from round 6, best verified).
// C = epi( A[M][K]i8 @ B[N][K]i8^T );  epi = sa[m]*s[n]*(acc + shift) + bias[n]
// 256x256 tile, BK=128B, 8 waves (2x4), wave 128x64 via 4x2 mfma 32x32x32_i8.
// LDS: sAB[buf][A 0..32K | B 32K..64K] x2 = 128 KiB dbuf; 16B-chunk XOR
// swizzle phys = logical ^ (row&7).  Counted lgkm(6) ks-phase pipeline,
// counted vmcnt(4), 2 barriers/tile, x2 unroll with lane-resident bases.
// ---------------------------------------------------------------------------
template <bool RELU, bool SHIFT, typename OutT>
__global__ __launch_bounds__(512, 2) void gemm_i8_256(
    const int8_t* __restrict__ A, const int8_t* __restrict__ B,
    OutT* __restrict__ C,
    const float* __restrict__ sa,      // per-m dequant scale
    const float* __restrict__ s,       // per-n scale
    const float* __restrict__ bias,    // per-n bias
    const int* __restrict__ wsum,      // per-n row-sum of B (SHIFT only)
    int M, int N, int K)
{
    __shared__ alignas(1024) char sAB[2][65536];

    const int tid  = threadIdx.x;
    const int lane = tid & 63;
    const int wave = tid >> 6;
    const int wm = wave >> 2;          // 0..1: row half (128 rows)
    const int wn = wave & 3;           // 0..3: col quarter (64 cols)

    // Column-major per-XCD mapping
    int bid = blockIdx.y * gridDim.x + blockIdx.x;
    const int xcd = bid & 7;
    const int idx = bid >> 3;
    const int cpx = gridDim.x >> 3;
    const int bx = xcd * cpx + idx / gridDim.y;
    const int by = idx % gridDim.y;
    const int bm = by * 256;
    const int bn = bx * 256;

    const int srow = tid >> 3;                        // 0..63
    const int scol = ((tid & 7) ^ (srow & 7)) << 4;
    const int ldst = tid * 16;
    const size_t rK64  = (size_t)64 * K;
    const size_t rK128 = (size_t)128 * K;

    const int8_t* gA = A + (size_t)(bm + srow) * K + scol;   // advances +=128/tile
    const int8_t* gB = B + (size_t)(bn + srow) * K + scol;

    auto stage_a = [&](int buf, int h) {
        const int8_t* g = gA + (size_t)h * rK128;
        char* l = &sAB[buf][h * 16384 + ldst];
        load_lds16(g, l);
        load_lds16(g + rK64, l + 8192);
    };
    auto stage_b = [&](int buf, int h) {
        const int8_t* g = gB + (size_t)h * rK128;
        char* l = &sAB[buf][32768 + h * 16384 + ldst];
        load_lds16(g, l);
        load_lds16(g + rK64, l + 8192);
    };

    // lane-resident read bases (zero per-read VALU; frag -> offset:imm)
    const int l31 = lane & 31;
    const int kh  = lane >> 5;
    const char* rdA[2][4];
    const char* rdB[2][4];
#pragma unroll
    for (int ks = 0; ks < 4; ++ks) {
        const int lp = l31 * 128 + ((((ks << 1) | kh) ^ (l31 & 7)) << 4);
        rdA[0][ks] = &sAB[0][wm * 16384 + lp];
        rdA[1][ks] = &sAB[1][wm * 16384 + lp];
        rdB[0][ks] = &sAB[0][32768 + wn * 8192 + lp];
        rdB[1][ks] = &sAB[1][32768 + wn * 8192 + lp];
    }

    i32x4 afX[4], afY[4], bfX[2], bfY[2];
    i32x16 acc[4][2] = {};
    const int NT = K >> 7;                 // 32 or 64 (always even)

#define SB0() __builtin_amdgcn_sched_barrier(0)
#define LG6  asm volatile("s_waitcnt lgkmcnt(6)" ::: "memory")
#define LG0  asm volatile("s_waitcnt lgkmcnt(0)" ::: "memory")
#define READF(AF, BF, BUF, KS)                                             \
    do {                                                                   \
        BF[0] = *(const i32x4*)(rdB[BUF][KS]);                             \
        BF[1] = *(const i32x4*)(rdB[BUF][KS] + 4096);                      \
        AF[0] = *(const i32x4*)(rdA[BUF][KS]);                             \
        AF[1] = *(const i32x4*)(rdA[BUF][KS] + 4096);                      \
        AF[2] = *(const i32x4*)(rdA[BUF][KS] + 8192);                      \
        AF[3] = *(const i32x4*)(rdA[BUF][KS] + 12288);                     \
    } while (0)
#define MFMA8(AF, BF)                                                      \
    do { __builtin_amdgcn_s_setprio(1);                                    \
        _Pragma("unroll")                                                  \
        for (int i_ = 0; i_ < 4; ++i_) {                                   \
            acc[i_][0] = __builtin_amdgcn_mfma_i32_32x32x32_i8(            \
                AF[i_], BF[0], acc[i_][0], 0, 0, 0);                       \
            acc[i_][1] = __builtin_amdgcn_mfma_i32_32x32x32_i8(            \
                AF[i_], BF[1], acc[i_][1], 0, 0, 0);                       \
        }                                                                  \
        __builtin_amdgcn_s_setprio(0); } while (0)

    // prologue: A(0)->buf0, B(0)->buf0, B(1)->buf1
    stage_a(0, 0); stage_a(0, 1); gA += 128;
    stage_b(0, 0); stage_b(0, 1); gB += 128;
    stage_b(1, 0); stage_b(1, 1); gB += 128;

    for (int t = 0; t < NT; t += 2) {
        const bool pf = (t + 2 < NT);

        // ================= tile t (buf 0) =================
        asm volatile("s_waitcnt vmcnt(4)" ::: "memory");
        __builtin_amdgcn_s_barrier();
        SB0();
        READF(afX, bfX, 0, 0);
        stage_a(1, 0); stage_a(1, 1); gA += 128;          // A(t+1)
        SB0();
        READF(afY, bfY, 0, 1); SB0(); LG6; SB0(); MFMA8(afX, bfX);
        READF(afX, bfX, 0, 2); SB0(); LG6; SB0(); MFMA8(afY, bfY);
        READF(afY, bfY, 0, 3); SB0(); LG6; SB0(); MFMA8(afX, bfX);
        LG0; SB0();
        __builtin_amdgcn_s_barrier();
        if (pf) { stage_b(0, 0); stage_b(0, 1); gB += 128; }   // B(t+2)
        SB0();
        MFMA8(afY, bfY);

        // ================= tile t+1 (buf 1) =================
        if (pf) asm volatile("s_waitcnt vmcnt(4)" ::: "memory");
        else    asm volatile("s_waitcnt vmcnt(0)" ::: "memory");
        __builtin_amdgcn_s_barrier();
        SB0();
        READF(afX, bfX, 1, 0);
        if (pf) { stage_a(0, 0); stage_a(0, 1); gA += 128; }   // A(t+2)
        SB0();
        READF(afY, bfY, 1, 1); SB0(); LG6; SB0(); MFMA8(afX, bfX);
        READF(afX, bfX, 1, 2); SB0(); LG6; SB0(); MFMA8(afY, bfY);
        READF(afY, bfY, 1, 3); SB0(); LG6; SB0(); MFMA8(afX, bfX);
        LG0; SB0();
        __builtin_amdgcn_s_barrier();
        if (pf) { stage_b(1, 0); stage_b(1, 1); gB += 128; }   // B(t+3)
        SB0();
        MFMA8(afY, bfY);
    }
#undef SB0
#undef LG6
#undef LG0
#undef READF
#undef MFMA8

    // epilogue: 32x32 C/D layout col=lane&31, row=(reg&3)+8*(reg>>2)+4*(lane>>5)
#pragma unroll
    for (int j = 0; j < 2; ++j) {
        const int n  = bn + wn * 64 + j * 32 + l31;
        const float sc = s[n];
        const float bs = bias[n];
        const int shf = SHIFT ? 128 * wsum[n] : 0;
#pragma unroll
        for (int i = 0; i < 4; ++i) {
            const int mb = bm + wm * 128 + i * 32 + 4 * kh;
#pragma unroll
            for (int reg = 0; reg < 16; ++reg) {
                const int m = mb + (reg & 3) + 8 * (reg >> 2);
                float v = (float)(acc[i][j][reg] + shf) * sc * sa[m] + bs;
                if (RELU) v = v > 0.f ? v : 0.f;
                C[(size_t)m * N + n] = (OutT)v;
            }
        }
    }
}

extern "C" void kernel_launch(void* const* d_in, const int* in_sizes, int n_in,
                              void* d_out, int out_size, void* d_ws, size_t ws_size,
                              hipStream_t stream)
{
    const float* x   = (const float*)d_in[0];
    const int4*  w1p = (const int4*)d_in[1];     // int8 widened to int32
    const float* s1  = (const float*)d_in[2];    // fp16 widened to fp32
    const float* b1  = (const float*)d_in[3];
    const int4*  w2p = (const int4*)d_in[4];
    const float* s2  = (const float*)d_in[5];
    const float* b2  = (const float*)d_in[6];
    float* out = (float*)d_out;

    const int d    = in_sizes[6];        // 4096
    const int d2   = in_sizes[3];        // 8192
    const int Ntok = in_sizes[0] / d;    // 4096

    const size_t sz_xq = (size_t)Ntok * d;            // 16.8 MB
    const size_t sz_w1 = (size_t)d2 * d;              // 33.6 MB
    const size_t sz_w2 = (size_t)d * d2;              // 33.6 MB
    const size_t sz_hb = (size_t)Ntok * d2 * 2;       // 67.1 MB
    const size_t sz_hq = (size_t)Ntok * d2;           // 33.6 MB
    const size_t sz_tail = (size_t)(2 * Ntok + d) * 4 + 4096;

    const size_t need_fused = sz_xq + sz_w1 + sz_w2 + sz_hb + sz_hq + sz_tail;

    char* ws = (char*)d_ws;
    if (ws_size >= need_fused) {
        // ---------------- fused layout ----------------
        int8_t*   xq  = (int8_t*)ws;
        int8_t*   wq1 = (int8_t*)(ws + sz_xq);
        int8_t*   wq2 = (int8_t*)(ws + sz_xq + sz_w1);
        _Float16* hb  = (_Float16*)(ws + sz_xq + sz_w1 + sz_w2);
        int8_t*   hq  = (int8_t*)((char*)hb + sz_hb);
        float*    sx  = (float*)((char*)hq + sz_hq);
        float*    sh  = sx + Ntok;
        int*      wsum = (int*)(sh + Ntok);

        // 1. fused prep: quant_x + expand W1 + expand W2 (+wsum)
        prep_fused<<<Ntok + d2 + d, 256, 0, stream>>>(
            x, (int4*)xq, sx, w1p, (int4*)wq1, w2p, (int4*)wq2,
            wsum, Ntok, d, d2);
        // 2. gemm1: h = relu(s1[n]*sx[m]*acc + b1[n]) -> f16
        {
            dim3 grid(d2 / 256, Ntok / 256);
            gemm_i8_256<true, false, _Float16><<<grid, 512, 0, stream>>>(
                xq, wq1, hb, sx, s1, b1, nullptr, Ntok, d2, d);
        }
        // 3. h -> shifted-u8 per-row
        quant_h<<<Ntok, 256, 0, stream>>>(hb, (int4*)hq, sh, d2);
        // 4. gemm2: out = s2[n]*sh[m]*(acc + 128*wsum[n]) + b2[n] -> f32
        {
            dim3 grid(d / 256, Ntok / 256);
            gemm_i8_256<false, true, float><<<grid, 512, 0, stream>>>(
                hq, wq2, out, sh, s2, b2, wsum, Ntok, d, d2);
        }
    } else {
        // ---------------- fallback: sequential layout (W1/W2 share wq) ----
        int8_t*   xq = (int8_t*)ws;
        int8_t*   wq = (int8_t*)(ws + sz_xq);
        _Float16* hb = (_Float16*)(ws + sz_xq + sz_w1);
        int8_t*   hq = (int8_t*)((char*)hb + sz_hb);
        float*    sx = (float*)((char*)hq + sz_hq);
        float*    sh = sx + Ntok;
        int*      wsum = (int*)(sh + Ntok);

        quant_x<<<Ntok, 256, 0, stream>>>(x, (int4*)xq, sx, d);
        expand_int4_i8<<<d2, 256, 0, stream>>>(w1p, (int4*)wq, wsum, d / 8);
        {
            dim3 grid(d2 / 256, Ntok / 256);
            gemm_i8_256<true, false, _Float16><<<grid, 512, 0, stream>>>(
                xq, wq, hb, sx, s1, b1, nullptr, Ntok, d2, d);
        }
        quant_h<<<Ntok, 256, 0, stream>>>(hb, (int4*)hq, sh, d2);
        expand_int4_i8<<<d, 256, 0, stream>>>(w2p, (int4*)wq, wsum, d2 / 8);
        {
            dim3 grid(d / 256, Ntok / 256);
            gemm_i8_256<false, true, float><<<grid, 512, 0, stream>>>(
                hq, wq, out, sh, s2, b2, wsum, Ntok, d, d2);
        }
    }
}